// Round 7
// baseline (262.982 us; speedup 1.0000x reference)
//
#include <hip/hip_runtime.h>

// Gated delta-rule recurrent cell, single step. B=128, H=16, Dk=Dv=128.
//
// Round-7: two-pass (round-6 structure) with a COPY-SHAPED rewrite pass.
// Round-6 arithmetic: P1+P2 ~= 86 us total, fabric 4.7 TB/s (vs fused
// kernels' 3.2) -> split is right, but P2 ran only ~4.3 TB/s because its
// inner loop cost 5 VMEM instructions per 16 B stored (S load, nt-store,
// plus per-iteration k/delta/decay loads) vs a copy's 2.
// Fix: block = one (b,h) tile; k-slice (16 scalars), delta f4, decay hoisted
// to registers OUTSIDE the loop (all loop-invariant per thread); inner loop
// is 16 x {f4 load -> 2 FMA -> f4 store}, 1KB contiguous per wave instr,
// REGULAR stores (fill=6.8 and copy=6.3 TB/s both use cache-allocating
// stores; nt bypass is the remaining untested difference).
// out[v] = decay*Bq[v] + (k.q)*delta[v]  (algebraic identity)

#define DK 128
#define DV 128
#define BH_MAX 2048
typedef float f4 __attribute__((ext_vector_type(4)));

// Inter-pass scratch: static device globals (no hipMalloc, no d_ws).
__device__ float g_delta[BH_MAX * DV];
__device__ float g_decay[BH_MAX];

// ---------------- Pass 1: reduce (one block per (b,h)) ----------------
__global__ __launch_bounds__(256) void s1_reduce_kernel(
    const float* __restrict__ q,
    const float* __restrict__ k,
    const float* __restrict__ v,
    const float* __restrict__ g,
    const float* __restrict__ beta,
    const float* __restrict__ S,
    float* __restrict__ out)        // d_out head: out[bh][v]
{
    const int bh   = blockIdx.x;
    const int w    = threadIdx.x >> 6;     // wave 0..3 -> rows [32w,32w+32)
    const int lane = threadIdx.x & 63;
    const int half = lane >> 5;            // row parity within pair
    const int c0   = (lane & 31) * 4;      // column (float idx)

    __shared__ float apart[4][DV];
    __shared__ float bpart[4][DV];
    __shared__ float skq[4];

    const float* __restrict__ Sb = S + (size_t)bh * (DK * DV);
    const int r0 = 32 * w + half;

    // contiguous 1KB wave loads: rows r0+2i (row pair fully covered)
    f4 s[16];
    #pragma unroll
    for (int i = 0; i < 16; ++i)
        s[i] = *(const f4*)(Sb + (size_t)(r0 + 2 * i) * DV + c0);

    float kv[16], qv[16];
    #pragma unroll
    for (int i = 0; i < 16; ++i) {
        kv[i] = k[bh * DK + r0 + 2 * i];
        qv[i] = q[bh * DK + r0 + 2 * i];
    }

    const float decay = expf(g[bh]);
    const float bta   = beta[bh];

    f4 a = {0.f, 0.f, 0.f, 0.f};
    f4 b = {0.f, 0.f, 0.f, 0.f};
    float kqp = 0.f;
    #pragma unroll
    for (int i = 0; i < 16; ++i) {
        a   += s[i] * kv[i];
        b   += s[i] * qv[i];
        kqp += kv[i] * qv[i];
    }

    // merge row parities (lane ^ 32)
    a.x += __shfl_xor(a.x, 32, 64);  a.y += __shfl_xor(a.y, 32, 64);
    a.z += __shfl_xor(a.z, 32, 64);  a.w += __shfl_xor(a.w, 32, 64);
    b.x += __shfl_xor(b.x, 32, 64);  b.y += __shfl_xor(b.y, 32, 64);
    b.z += __shfl_xor(b.z, 32, 64);  b.w += __shfl_xor(b.w, 32, 64);
    kqp += __shfl_xor(kqp, 32, 64);

    if (lane < 32) {
        *(f4*)&apart[w][c0] = a;
        *(f4*)&bpart[w][c0] = b;
        if (lane == 0) skq[w] = kqp;
    }
    __syncthreads();

    if (w == 0 && lane < 32) {
        f4 A  = *(const f4*)&apart[0][c0];
        f4 Bq = *(const f4*)&bpart[0][c0];
        #pragma unroll
        for (int j = 1; j < 4; ++j) {
            A  += *(const f4*)&apart[j][c0];
            Bq += *(const f4*)&bpart[j][c0];
        }
        const float kq = skq[0] + skq[1] + skq[2] + skq[3];

        const f4 vv  = *(const f4*)(v + bh * DV + c0);
        const f4 dlt = (vv - decay * A) * bta;

        *(f4*)(g_delta + (size_t)bh * DV + c0) = dlt;
        *(f4*)(out + (size_t)bh * DV + c0)     = decay * Bq + kq * dlt;
        if (lane == 0) g_decay[bh] = decay;
    }
}

// ------- Pass 2: rewrite — copy-shaped, one block per (b,h) tile -------
// Thread t handles f4-indices t + 256*i (i=0..15) of its tile: per wave
// instruction that's 1KB contiguous; iteration stride 4KB. Loop-invariant
// operands: row(i) = (t>>5) + 8*i -> kv[16] scalars; col = (t&31)*4 ->
// one delta f4; decay scalar. Inner loop: load f4, 2 FMA, store f4. Nothing
// else. Regular (cache-allocating) stores.
__global__ __launch_bounds__(256) void s1_rewrite_kernel(
    const float* __restrict__ k,
    const float* __restrict__ S,
    float* __restrict__ outS)       // d_out + BH*DV
{
    const int bh = blockIdx.x;
    const int t  = threadIdx.x;

    const size_t base = (size_t)bh * (DK * DV / 4) + t;   // f4 index
    const f4* __restrict__ Sp = (const f4*)S + base;
    f4* __restrict__ Op       = (f4*)outS + base;

    const int r0 = t >> 5;               // row of iteration 0 (rows step by 8)
    const int vc = (t & 31) * 4;         // fixed column group

    float kv[16];
    #pragma unroll
    for (int i = 0; i < 16; ++i)
        kv[i] = k[bh * DK + r0 + 8 * i];

    const float dec = g_decay[bh];
    const f4    dlt = *(const f4*)(g_delta + (size_t)bh * DV + vc);

    #pragma unroll
    for (int i = 0; i < 16; ++i) {
        const f4 s = Sp[256 * i];
        Op[256 * i] = dec * s + kv[i] * dlt;
    }
}

extern "C" void kernel_launch(void* const* d_in, const int* in_sizes, int n_in,
                              void* d_out, int out_size, void* d_ws, size_t ws_size,
                              hipStream_t stream) {
    const float* q    = (const float*)d_in[0];
    const float* k    = (const float*)d_in[1];
    const float* v    = (const float*)d_in[2];
    const float* g    = (const float*)d_in[3];
    const float* beta = (const float*)d_in[4];
    const float* S    = (const float*)d_in[5];
    float* out = (float*)d_out;

    const int BH = in_sizes[3];   // g has B*H elements = 2048 (<= BH_MAX)

    s1_reduce_kernel<<<BH, 256, 0, stream>>>(q, k, v, g, beta, S, out);
    s1_rewrite_kernel<<<BH, 256, 0, stream>>>(k, S, out + (size_t)BH * DV);
}

// Round 8
// 239.547 us; speedup vs baseline: 1.0978x; 1.0978x over previous
//
#include <hip/hip_runtime.h>

// Gated delta-rule recurrent cell, single step. B=128, H=16, Dk=Dv=128.
//
// Round-8: FUSED again (best known structure = round 4, 82 us), plus the two
// untried levers against the ~2.5 TB/s wall that held across 8 structures:
//  1) NONTEMPORAL LOADS for S: S is read exactly once per iteration; `nt`
//     streaming loads skip L1/L2 allocation (deeper streaming path, no
//     miss-slot pressure). Theory: the wall = per-CU outstanding-line cap
//     (~32 lines x 128B / 900cyc ~= 2.6 TB/s chip) on the allocating path.
//  2) CROSS-TILE R/W OVERLAP: each block processes TWO (b,h) tiles; tile-1's
//     16 wave-loads are issued BEFORE tile-0's 16 wave-stores, so reads and
//     writes are concurrently in flight at every tile transition.
// Lane layout per tile (round-4): wave w rows [32w,32w+32), half=lane>>5,
// c0=(lane&31)*4; every S load/store is one contiguous 1KB wave instruction.
// out[v] = decay*Bq[v] + (k.q)*delta[v]  (algebraic identity, single pass)

#define DK 128
#define DV 128
typedef float f4 __attribute__((ext_vector_type(4)));

__global__ __launch_bounds__(256) void s1_cell_kernel(
    const float* __restrict__ q,
    const float* __restrict__ k,
    const float* __restrict__ v,
    const float* __restrict__ g,
    const float* __restrict__ beta,
    const float* __restrict__ S,
    float* __restrict__ out,      // full d_out
    int BH)
{
    const int w    = threadIdx.x >> 6;     // wave 0..3 -> rows [32w,32w+32)
    const int lane = threadIdx.x & 63;
    const int half = lane >> 5;            // row parity within pair
    const int c0   = (lane & 31) * 4;      // column (float idx)
    const int r0   = 32 * w + half;        // lane's base row

    __shared__ float apart[4][DV];
    __shared__ float bpart[4][DV];
    __shared__ float skq[4];

    const int bh0 = blockIdx.x;
    const int bh1 = blockIdx.x + gridDim.x;

    // ================= tile 0: load (nt) =================
    const float* __restrict__ Sb0 = S + (size_t)bh0 * (DK * DV);
    f4 s0[16];
    #pragma unroll
    for (int i = 0; i < 16; ++i)
        s0[i] = __builtin_nontemporal_load(
                    (const f4*)(Sb0 + (size_t)(r0 + 2 * i) * DV + c0));

    float kv0[16];
    #pragma unroll
    for (int i = 0; i < 16; ++i)
        kv0[i] = k[bh0 * DK + r0 + 2 * i];

    const float dec0 = expf(g[bh0]);
    const float bt0  = beta[bh0];

    f4 a = {0.f, 0.f, 0.f, 0.f};
    f4 b = {0.f, 0.f, 0.f, 0.f};
    float kqp = 0.f;
    #pragma unroll
    for (int i = 0; i < 16; ++i) {
        const float qv = q[bh0 * DK + r0 + 2 * i];
        a   += s0[i] * kv0[i];
        b   += s0[i] * qv;
        kqp += kv0[i] * qv;
    }
    a.x += __shfl_xor(a.x, 32, 64);  a.y += __shfl_xor(a.y, 32, 64);
    a.z += __shfl_xor(a.z, 32, 64);  a.w += __shfl_xor(a.w, 32, 64);
    b.x += __shfl_xor(b.x, 32, 64);  b.y += __shfl_xor(b.y, 32, 64);
    b.z += __shfl_xor(b.z, 32, 64);  b.w += __shfl_xor(b.w, 32, 64);
    kqp += __shfl_xor(kqp, 32, 64);
    if (lane < 32) {
        *(f4*)&apart[w][c0] = a;
        *(f4*)&bpart[w][c0] = b;
        if (lane == 0) skq[w] = kqp;
    }
    __syncthreads();

    f4 A  = *(const f4*)&apart[0][c0];
    f4 Bq = *(const f4*)&bpart[0][c0];
    #pragma unroll
    for (int j = 1; j < 4; ++j) {
        A  += *(const f4*)&apart[j][c0];
        Bq += *(const f4*)&bpart[j][c0];
    }
    const float kq0 = skq[0] + skq[1] + skq[2] + skq[3];
    const f4 vv0  = *(const f4*)(v + bh0 * DV + c0);
    const f4 dlt0 = (vv0 - dec0 * A) * bt0;
    if (w == 0 && lane < 32)
        *(f4*)(out + (size_t)bh0 * DV + c0) = dec0 * Bq + kq0 * dlt0;

    // ============ tile 1: issue loads BEFORE tile-0 stores ============
    const bool has1 = (bh1 < BH);
    const float* __restrict__ Sb1 = S + (size_t)bh1 * (DK * DV);
    f4 s1[16];
    if (has1) {
        #pragma unroll
        for (int i = 0; i < 16; ++i)
            s1[i] = __builtin_nontemporal_load(
                        (const f4*)(Sb1 + (size_t)(r0 + 2 * i) * DV + c0));
    }

    // ============ tile 0: stores (tile-1 reads in flight) ============
    float* __restrict__ oS0 = out + (size_t)BH * DV + (size_t)bh0 * (DK * DV);
    #pragma unroll
    for (int i = 0; i < 16; ++i)
        *(f4*)(oS0 + (size_t)(r0 + 2 * i) * DV + c0)
            = dec0 * s0[i] + kv0[i] * dlt0;

    if (!has1) return;

    // ================= tile 1: reduce + store =================
    float kv1[16];
    #pragma unroll
    for (int i = 0; i < 16; ++i)
        kv1[i] = k[bh1 * DK + r0 + 2 * i];

    const float dec1 = expf(g[bh1]);
    const float bt1  = beta[bh1];

    a = (f4){0.f, 0.f, 0.f, 0.f};
    b = (f4){0.f, 0.f, 0.f, 0.f};
    kqp = 0.f;
    #pragma unroll
    for (int i = 0; i < 16; ++i) {
        const float qv = q[bh1 * DK + r0 + 2 * i];
        a   += s1[i] * kv1[i];
        b   += s1[i] * qv;
        kqp += kv1[i] * qv;
    }
    a.x += __shfl_xor(a.x, 32, 64);  a.y += __shfl_xor(a.y, 32, 64);
    a.z += __shfl_xor(a.z, 32, 64);  a.w += __shfl_xor(a.w, 32, 64);
    b.x += __shfl_xor(b.x, 32, 64);  b.y += __shfl_xor(b.y, 32, 64);
    b.z += __shfl_xor(b.z, 32, 64);  b.w += __shfl_xor(b.w, 32, 64);
    kqp += __shfl_xor(kqp, 32, 64);

    __syncthreads();                     // protect apart/bpart reuse
    if (lane < 32) {
        *(f4*)&apart[w][c0] = a;
        *(f4*)&bpart[w][c0] = b;
        if (lane == 0) skq[w] = kqp;
    }
    __syncthreads();

    A  = *(const f4*)&apart[0][c0];
    Bq = *(const f4*)&bpart[0][c0];
    #pragma unroll
    for (int j = 1; j < 4; ++j) {
        A  += *(const f4*)&apart[j][c0];
        Bq += *(const f4*)&bpart[j][c0];
    }
    const float kq1 = skq[0] + skq[1] + skq[2] + skq[3];
    const f4 vv1  = *(const f4*)(v + bh1 * DV + c0);
    const f4 dlt1 = (vv1 - dec1 * A) * bt1;
    if (w == 0 && lane < 32)
        *(f4*)(out + (size_t)bh1 * DV + c0) = dec1 * Bq + kq1 * dlt1;

    float* __restrict__ oS1 = out + (size_t)BH * DV + (size_t)bh1 * (DK * DV);
    #pragma unroll
    for (int i = 0; i < 16; ++i)
        *(f4*)(oS1 + (size_t)(r0 + 2 * i) * DV + c0)
            = dec1 * s1[i] + kv1[i] * dlt1;
}

extern "C" void kernel_launch(void* const* d_in, const int* in_sizes, int n_in,
                              void* d_out, int out_size, void* d_ws, size_t ws_size,
                              hipStream_t stream) {
    const float* q    = (const float*)d_in[0];
    const float* k    = (const float*)d_in[1];
    const float* v    = (const float*)d_in[2];
    const float* g    = (const float*)d_in[3];
    const float* beta = (const float*)d_in[4];
    const float* S    = (const float*)d_in[5];
    float* out = (float*)d_out;

    const int BH = in_sizes[3];   // g has B*H elements = 2048

    // half-grid, 2 tiles per block (bh and bh + gridDim)
    const int nblk = (BH + 1) / 2;
    s1_cell_kernel<<<nblk, 256, 0, stream>>>(q, k, v, g, beta, S, out, BH);
}